// Round 3
// baseline (2868.158 us; speedup 1.0000x reference)
//
#include <hip/hip_runtime.h>
#include <stdint.h>

// Problem constants (GRU_12764642803875)
#define Bsz 8
#define Ssz 1024
#define STATEsz 1024
#define Hsz 8
#define Dsz 128

typedef float  f32x4  __attribute__((ext_vector_type(4)));
typedef int    i32x4  __attribute__((ext_vector_type(4)));
typedef __bf16 bf16x8 __attribute__((ext_vector_type(8)));

__device__ __forceinline__ unsigned short f2bf(float f){
  unsigned int u = __float_as_uint(f);
  u = u + 0x7FFFu + ((u >> 16) & 1u);   // round-to-nearest-even
  return (unsigned short)(u >> 16);
}
__device__ __forceinline__ float bf2f(unsigned short s){
  return __uint_as_float(((unsigned int)s) << 16);
}
__device__ __forceinline__ float sigmoid_(float x){ return 1.f/(1.f+__expf(-x)); }
__device__ __forceinline__ float tanh_(float x){ return 2.f/(1.f+__expf(-2.f*x)) - 1.f; }

// ---------------- fp32 -> bf16 cast, 4-wide ----------------
__global__ void k_cast_bf16(const float* __restrict__ in, unsigned short* __restrict__ out, int n4){
  int i = blockIdx.x*blockDim.x + threadIdx.x;
  if (i >= n4) return;
  f32x4 v = ((const f32x4*)in)[i];
  ushort4 o;
  o.x = f2bf(v[0]); o.y = f2bf(v[1]); o.z = f2bf(v[2]); o.w = f2bf(v[3]);
  ((ushort4*)out)[i] = o;
}

// ---------------- fp32 [R][C] -> bf16 [C][R] transpose ----------------
__global__ void k_transpose_bf16(const float* __restrict__ in, unsigned short* __restrict__ out, int R, int C){
  __shared__ float tile[32][33];
  int c0 = blockIdx.x*32, r0 = blockIdx.y*32;
  int tx = threadIdx.x, ty = threadIdx.y;   // block (32,8)
  #pragma unroll
  for (int i=0;i<4;++i) tile[ty+8*i][tx] = in[(size_t)(r0+ty+8*i)*C + c0+tx];
  __syncthreads();
  #pragma unroll
  for (int i=0;i<4;++i) out[(size_t)(c0+ty+8*i)*R + r0+tx] = f2bf(tile[tx][ty+8*i]);
}

// ---------------- bf16 MFMA GEMM: C[M,N] = A[M,K] @ Bt[N,K]^T (+bias) ----------------
// MODE 0: f32 C row-major.  MODE 1: bf16 C row-major.
// MODE 2: bf16 scatter into projT[h][t][g][b][e] (N must be 3072, M = B*S).
template<int MODE, bool BIAS>
__global__ __launch_bounds__(256) void k_gemm(
    const unsigned short* __restrict__ A, const unsigned short* __restrict__ Bt,
    const float* __restrict__ bias, unsigned short* __restrict__ Cb, float* __restrict__ Cf,
    int M, int N, int K){
  __shared__ unsigned short As[128][40];
  __shared__ unsigned short Bs[128][40];
  int t = threadIdx.x;
  int l = t & 63, w = t >> 6, wm = w >> 1, wn = w & 1;
  int m0 = blockIdx.y*128, n0 = blockIdx.x*128;
  f32x4 acc[4][4];
  #pragma unroll
  for(int a=0;a<4;++a)
    #pragma unroll
    for(int b=0;b<4;++b){ acc[a][b][0]=0.f; acc[a][b][1]=0.f; acc[a][b][2]=0.f; acc[a][b][3]=0.f; }
  int lr = l & 15, lk = (l >> 4)*8;
  for(int k0=0;k0<K;k0+=32){
    #pragma unroll
    for(int it=0; it<2; ++it){              // stage 128x32 bf16 for A and Bt
      int idx = t + 256*it, r = idx>>2, q = idx&3;
      i32x4 av = *(const i32x4*)(A  + (size_t)(m0+r)*K + k0 + q*8);
      i32x4 bv = *(const i32x4*)(Bt + (size_t)(n0+r)*K + k0 + q*8);
      *(i32x4*)(&As[r][q*8]) = av;
      *(i32x4*)(&Bs[r][q*8]) = bv;
    }
    __syncthreads();
    bf16x8 af[4], bfv[4];
    #pragma unroll
    for(int mi=0;mi<4;++mi) af[mi]  = *(const bf16x8*)(&As[wm*64+mi*16+lr][lk]);
    #pragma unroll
    for(int ni=0;ni<4;++ni) bfv[ni] = *(const bf16x8*)(&Bs[wn*64+ni*16+lr][lk]);
    #pragma unroll
    for(int mi=0;mi<4;++mi)
      #pragma unroll
      for(int ni=0;ni<4;++ni)
        acc[mi][ni] = __builtin_amdgcn_mfma_f32_16x16x32_bf16(af[mi], bfv[ni], acc[mi][ni], 0,0,0);
    __syncthreads();
  }
  // C/D layout: col = lane&15, row = (lane>>4)*4 + j  [m89-verified]
  int cr0 = (l>>4)*4;
  #pragma unroll
  for(int mi=0;mi<4;++mi){
    #pragma unroll
    for(int ni=0;ni<4;++ni){
      int col = n0 + wn*64 + ni*16 + lr;
      float bv = BIAS ? bias[col] : 0.f;
      #pragma unroll
      for(int j=0;j<4;++j){
        int row = m0 + wm*64 + mi*16 + cr0 + j;
        float v = acc[mi][ni][j] + bv;
        if (MODE == 0) Cf[(size_t)row*N + col] = v;
        else if (MODE == 1) Cb[(size_t)row*N + col] = f2bf(v);
        else {
          // scatter: row=(b,t), col=(g,h,e) -> projT[((h*1024+t)*3+g)*1024 + b*128 + e]
          int b = row >> 10, tt = row & 1023;
          int g = col >> 10, hh = (col >> 7) & 7, e = col & 127;
          size_t idx = ((((size_t)hh*1024 + tt)*3 + g) << 10) + b*128 + e;
          Cb[idx] = f2bf(v);
        }
      }
    }
  }
}

// ---------------- recurrence via MFMA: 8 blocks (one per head), 512 threads ----------------
// wave w owns output cols [16w,16w+16). M=16 rows = 8 batches + 8 zero-pad.
// Weights as B-frags in VGPRs (3 gates x 4 ksteps x 8 bf16). h mirrored in LDS
// [16][136] bf16 A-layout (272B row stride: 16B-aligned, 4-bank/row rotation).
// 2 raw s_barriers/step with lgkmcnt(0) only -> global gate prefetch stays in flight.
__global__ __launch_bounds__(512) void k_rnn_mfma(
    const unsigned short* __restrict__ projT,  // [8][1024][3][8][128] bf16
    const float* __restrict__ h0,
    const float* __restrict__ Wst, const float* __restrict__ Wfg, const float* __restrict__ Wrs,
    unsigned short* __restrict__ hs, float* __restrict__ hT){
  const int h = blockIdx.x;            // head
  const int t0 = threadIdx.x;
  const int l = t0 & 63, w = t0 >> 6;  // lane, wave
  const int lr = l & 15;               // A-row / C-col (within tile)
  const int lg = l >> 4;               // quarter-wave group
  const int e  = 16*w + lr;            // state column this lane owns (d index)

  __shared__ unsigned short h_a[16][136];
  __shared__ unsigned short rh_a[16][136];

  // ---- weight B-frags: lane holds B[k=lg*8+j][col=lr] of n-tile w, kstep k ----
  bf16x8 wbR[4], wbF[4], wbS[4];
  {
    const float* pR = Wrs + h*16384;
    const float* pF = Wfg + h*16384;
    const float* pS = Wst + h*16384;
    #pragma unroll
    for(int k=0;k<4;++k){
      #pragma unroll
      for(int j=0;j<8;++j){
        int d = 32*k + lg*8 + j;
        wbR[k][j] = (__bf16)pR[d*128 + e];
        wbF[k][j] = (__bf16)pF[d*128 + e];
        wbS[k][j] = (__bf16)pS[d*128 + e];
      }
    }
  }

  // ---- init h (C-layout regs: rows b=lg*4+j, col e) + LDS mirror ----
  float hc[4];
  #pragma unroll
  for(int j=0;j<4;++j){
    int b = lg*4 + j;
    hc[j] = (b < 8) ? h0[b*STATEsz + h*Dsz + e] : 0.f;
    h_a[b][e] = f2bf(hc[j]);
  }

  const unsigned short* ptbase = projT + ((size_t)h*Ssz)*3072;
  auto load_gates = [&](int tt, float* Z, float* F, float* R){
    const unsigned short* p = ptbase + (size_t)tt*3072;
    #pragma unroll
    for(int j=0;j<4;++j){
      int b = lg*4 + j;
      if (b < 8){
        Z[j] = bf2f(p[0*1024 + b*128 + e]);
        F[j] = bf2f(p[1*1024 + b*128 + e]);
        R[j] = bf2f(p[2*1024 + b*128 + e]);
      } else { Z[j]=0.f; F[j]=0.f; R[j]=0.f; }
    }
  };
  float zc[4], fc[4], rc[4], zn[4], fn[4], rn[4];
  load_gates(0, zc, fc, rc);
  __syncthreads();

  for(int st=0; st<Ssz; ++st){
    // A-frags of h
    bf16x8 af[4];
    #pragma unroll
    for(int k=0;k<4;++k) af[k] = *(const bf16x8*)(&h_a[lr][32*k + lg*8]);
    f32x4 aR = {0.f,0.f,0.f,0.f}, aF = {0.f,0.f,0.f,0.f};
    #pragma unroll
    for(int k=0;k<4;++k){
      aR = __builtin_amdgcn_mfma_f32_16x16x32_bf16(af[k], wbR[k], aR, 0,0,0);
      aF = __builtin_amdgcn_mfma_f32_16x16x32_bf16(af[k], wbF[k], aF, 0,0,0);
    }
    // prefetch next step's gate inputs (stays in flight across raw barriers)
    if (st+1 < Ssz){
      load_gates(st+1, zn, fn, rn);
    } else {
      #pragma unroll
      for(int j=0;j<4;++j){ zn[j]=0.f; fn[j]=0.f; rn[j]=0.f; }
    }
    // gates + r*h
    float ff[4];
    #pragma unroll
    for(int j=0;j<4;++j){
      float r = sigmoid_(rc[j] + aR[j]);
      ff[j]   = sigmoid_(fc[j] + aF[j]);
      rh_a[lg*4+j][e] = f2bf(r * hc[j]);
    }
    asm volatile("s_waitcnt lgkmcnt(0)" ::: "memory");
    __builtin_amdgcn_s_barrier();
    asm volatile("" ::: "memory");
    // candidate matvec on r*h
    bf16x8 arf[4];
    #pragma unroll
    for(int k=0;k<4;++k) arf[k] = *(const bf16x8*)(&rh_a[lr][32*k + lg*8]);
    f32x4 aC = {0.f,0.f,0.f,0.f};
    #pragma unroll
    for(int k=0;k<4;++k)
      aC = __builtin_amdgcn_mfma_f32_16x16x32_bf16(arf[k], wbS[k], aC, 0,0,0);
    #pragma unroll
    for(int j=0;j<4;++j){
      float c = tanh_(zc[j] + aC[j]);
      hc[j] = ff[j]*hc[j] + (1.f - ff[j])*c;
    }
    // publish h (LDS for next step, global for GEMM2)
    #pragma unroll
    for(int j=0;j<4;++j){
      int b = lg*4 + j;
      unsigned short hb = f2bf(hc[j]);
      h_a[b][e] = hb;
      if (b < 8) hs[(((size_t)b*Ssz + st) << 10) + h*Dsz + e] = hb;
      zc[j]=zn[j]; fc[j]=fn[j]; rc[j]=rn[j];
    }
    asm volatile("s_waitcnt lgkmcnt(0)" ::: "memory");
    __builtin_amdgcn_s_barrier();
    asm volatile("" ::: "memory");
  }
  #pragma unroll
  for(int j=0;j<4;++j){
    int b = lg*4 + j;
    if (b < 8) hT[b*STATEsz + h*Dsz + e] = hc[j];
  }
}

// ---------------- launch ----------------
// ws layout (bytes):                      size
//   xbf   @ 0          bf16[8192*1024]    16,777,216
//   WiT   @ 16777216   bf16[3072*1024]     6,291,456
//   WoT   @ 23068672   bf16[1024*1024]     2,097,152
//   projT @ 25165824   bf16[8*1024*3*8*128] 50,331,648
//   hs    @ 75497472   bf16[8192*1024]    16,777,216
// total 92,274,688 B
extern "C" void kernel_launch(void* const* d_in, const int* in_sizes, int n_in,
                              void* d_out, int out_size, void* d_ws, size_t ws_size,
                              hipStream_t stream){
  const float* x   = (const float*)d_in[0];
  const float* h0  = (const float*)d_in[1];
  const float* Wi  = (const float*)d_in[2];
  const float* bi  = (const float*)d_in[3];
  const float* Wst = (const float*)d_in[4];
  const float* Wfg = (const float*)d_in[5];
  const float* Wrs = (const float*)d_in[6];
  const float* Wo  = (const float*)d_in[7];
  float* out = (float*)d_out;
  float* hT  = out + (size_t)Bsz*Ssz*1024;

  char* ws = (char*)d_ws;
  unsigned short* xbf   = (unsigned short*)(ws);
  unsigned short* WiT   = (unsigned short*)(ws + 16777216);
  unsigned short* WoT   = (unsigned short*)(ws + 23068672);
  unsigned short* projT = (unsigned short*)(ws + 25165824);
  unsigned short* hsb   = (unsigned short*)(ws + 75497472);

  k_cast_bf16<<<dim3(8192), dim3(256), 0, stream>>>(x, xbf, 2097152);
  k_transpose_bf16<<<dim3(3072/32, 1024/32), dim3(32,8), 0, stream>>>(Wi, WiT, 1024, 3072);
  k_transpose_bf16<<<dim3(1024/32, 1024/32), dim3(32,8), 0, stream>>>(Wo, WoT, 1024, 1024);
  k_gemm<2,true><<<dim3(3072/128, 8192/128), dim3(256), 0, stream>>>(
      xbf, WiT, bi, projT, nullptr, 8192, 3072, 1024);
  k_rnn_mfma<<<dim3(8), dim3(512), 0, stream>>>(projT, h0, Wst, Wfg, Wrs, hsb, hT);
  k_gemm<0,false><<<dim3(1024/128, 8192/128), dim3(256), 0, stream>>>(
      hsb, WoT, nullptr, nullptr, out, 8192, 1024, 1024);
}

// Round 4
// 1902.773 us; speedup vs baseline: 1.5074x; 1.5074x over previous
//
#include <hip/hip_runtime.h>
#include <stdint.h>

// Problem constants (GRU_12764642803875)
#define Bsz 8
#define Ssz 1024
#define STATEsz 1024
#define Hsz 8
#define Dsz 128

typedef float  f32x4  __attribute__((ext_vector_type(4)));
typedef int    i32x4  __attribute__((ext_vector_type(4)));
typedef __bf16 bf16x8 __attribute__((ext_vector_type(8)));

__device__ __forceinline__ unsigned short f2bf(float f){
  unsigned int u = __float_as_uint(f);
  u = u + 0x7FFFu + ((u >> 16) & 1u);   // round-to-nearest-even
  return (unsigned short)(u >> 16);
}
__device__ __forceinline__ float bf2f(unsigned short s){
  return __uint_as_float(((unsigned int)s) << 16);
}
__device__ __forceinline__ float loF(unsigned int v){ return __uint_as_float(v << 16); }
__device__ __forceinline__ float hiF(unsigned int v){ return __uint_as_float(v & 0xffff0000u); }
__device__ __forceinline__ float sigmoid_(float x){ return 1.f/(1.f+__expf(-x)); }
__device__ __forceinline__ float tanh_(float x){ return 2.f/(1.f+__expf(-2.f*x)) - 1.f; }

// ---------------- fp32 -> bf16 cast, 4-wide ----------------
__global__ void k_cast_bf16(const float* __restrict__ in, unsigned short* __restrict__ out, int n4){
  int i = blockIdx.x*blockDim.x + threadIdx.x;
  if (i >= n4) return;
  f32x4 v = ((const f32x4*)in)[i];
  ushort4 o;
  o.x = f2bf(v[0]); o.y = f2bf(v[1]); o.z = f2bf(v[2]); o.w = f2bf(v[3]);
  ((ushort4*)out)[i] = o;
}

// ---------------- fp32 [R][C] -> bf16 [C][R] transpose ----------------
__global__ void k_transpose_bf16(const float* __restrict__ in, unsigned short* __restrict__ out, int R, int C){
  __shared__ float tile[32][33];
  int c0 = blockIdx.x*32, r0 = blockIdx.y*32;
  int tx = threadIdx.x, ty = threadIdx.y;   // block (32,8)
  #pragma unroll
  for (int i=0;i<4;++i) tile[ty+8*i][tx] = in[(size_t)(r0+ty+8*i)*C + c0+tx];
  __syncthreads();
  #pragma unroll
  for (int i=0;i<4;++i) out[(size_t)(c0+ty+8*i)*R + r0+tx] = f2bf(tile[tx][ty+8*i]);
}

// ---------------- bf16 MFMA GEMM: C[M,N] = A[M,K] @ Bt[N,K]^T (+bias) ----------------
// MODE 0: f32 C row-major.  MODE 1: bf16 C row-major.
// MODE 2: bf16 scatter into projT[h][t][g][b][(d>>5)*32 + (d&15)*2 + ((d>>4)&1)]
//         (n-pair-packed so the rnn kernel loads each gate pair as one dword).
template<int MODE, bool BIAS>
__global__ __launch_bounds__(256) void k_gemm(
    const unsigned short* __restrict__ A, const unsigned short* __restrict__ Bt,
    const float* __restrict__ bias, unsigned short* __restrict__ Cb, float* __restrict__ Cf,
    int M, int N, int K){
  __shared__ unsigned short As[128][40];
  __shared__ unsigned short Bs[128][40];
  int t = threadIdx.x;
  int l = t & 63, w = t >> 6, wm = w >> 1, wn = w & 1;
  int m0 = blockIdx.y*128, n0 = blockIdx.x*128;
  f32x4 acc[4][4];
  #pragma unroll
  for(int a=0;a<4;++a)
    #pragma unroll
    for(int b=0;b<4;++b){ acc[a][b][0]=0.f; acc[a][b][1]=0.f; acc[a][b][2]=0.f; acc[a][b][3]=0.f; }
  int lr = l & 15, lk = (l >> 4)*8;
  for(int k0=0;k0<K;k0+=32){
    #pragma unroll
    for(int it=0; it<2; ++it){              // stage 128x32 bf16 for A and Bt
      int idx = t + 256*it, r = idx>>2, q = idx&3;
      i32x4 av = *(const i32x4*)(A  + (size_t)(m0+r)*K + k0 + q*8);
      i32x4 bv = *(const i32x4*)(Bt + (size_t)(n0+r)*K + k0 + q*8);
      *(i32x4*)(&As[r][q*8]) = av;
      *(i32x4*)(&Bs[r][q*8]) = bv;
    }
    __syncthreads();
    bf16x8 af[4], bfv[4];
    #pragma unroll
    for(int mi=0;mi<4;++mi) af[mi]  = *(const bf16x8*)(&As[wm*64+mi*16+lr][lk]);
    #pragma unroll
    for(int ni=0;ni<4;++ni) bfv[ni] = *(const bf16x8*)(&Bs[wn*64+ni*16+lr][lk]);
    #pragma unroll
    for(int mi=0;mi<4;++mi)
      #pragma unroll
      for(int ni=0;ni<4;++ni)
        acc[mi][ni] = __builtin_amdgcn_mfma_f32_16x16x32_bf16(af[mi], bfv[ni], acc[mi][ni], 0,0,0);
    __syncthreads();
  }
  // C/D layout: col = lane&15, row = (lane>>4)*4 + j  [m89-verified]
  int cr0 = (l>>4)*4;
  #pragma unroll
  for(int mi=0;mi<4;++mi){
    #pragma unroll
    for(int ni=0;ni<4;++ni){
      int col = n0 + wn*64 + ni*16 + lr;
      float bv = BIAS ? bias[col] : 0.f;
      #pragma unroll
      for(int j=0;j<4;++j){
        int row = m0 + wm*64 + mi*16 + cr0 + j;
        float v = acc[mi][ni][j] + bv;
        if (MODE == 0) Cf[(size_t)row*N + col] = v;
        else if (MODE == 1) Cb[(size_t)row*N + col] = f2bf(v);
        else {
          int b = row >> 10, tt = row & 1023;
          int g = col >> 10, hh = (col >> 7) & 7, d = col & 127;
          size_t idx = ((((size_t)hh*1024 + tt)*3 + g) << 10)
                     + b*128 + (d>>5)*32 + (d&15)*2 + ((d>>4)&1);
          Cb[idx] = f2bf(v);
        }
      }
    }
  }
}

// ---------------- recurrence via MFMA: 8 blocks (one per head), 256 threads ----------------
// 4 waves; wave w owns cols [32w, 32w+32) as 2 ntiles of 16. M=16 = 8 batch + 8 pad.
// B-frags (3 gates x 2 ntiles x 4 ksteps) resident in regs. h/rh exchanged via LDS
// [16][136] (272B stride: conflict-free per 16-lane group). Depth-2 gate prefetch in
// packed dword buffers; 2 raw s_barriers/step with lgkmcnt(0) only (vmcnt in flight).
__global__ __launch_bounds__(256, 1) void k_rnn_mfma(
    const unsigned short* __restrict__ projT,  // [8][1024][3][8][128-packed] bf16
    const float* __restrict__ h0,
    const float* __restrict__ Wst, const float* __restrict__ Wfg, const float* __restrict__ Wrs,
    unsigned short* __restrict__ hs, float* __restrict__ hT){
  const int h = blockIdx.x;            // head
  const int t0 = threadIdx.x;
  const int l = t0 & 63, w = t0 >> 6;  // lane, wave (0..3)
  const int lr = l & 15;               // A-row / C-col (within tile)
  const int lg = l >> 4;               // quarter-wave group

  __shared__ unsigned short h_a[16][136];
  __shared__ unsigned short rh_a[16][136];

  // ---- weight B-frags: [ntile][kstep]; lane holds W[din=32k+8lg+j][col=32w+16n+lr] ----
  bf16x8 wbR[2][4], wbF[2][4], wbS[2][4];
  {
    const float* pR = Wrs + h*16384;
    const float* pF = Wfg + h*16384;
    const float* pS = Wst + h*16384;
    #pragma unroll
    for(int n=0;n<2;++n){
      int col = 32*w + 16*n + lr;
      #pragma unroll
      for(int k=0;k<4;++k){
        #pragma unroll
        for(int j=0;j<8;++j){
          int din = 32*k + 8*lg + j;
          wbR[n][k][j] = (__bf16)pR[din*128 + col];
          wbF[n][k][j] = (__bf16)pF[din*128 + col];
          wbS[n][k][j] = (__bf16)pS[din*128 + col];
        }
      }
    }
  }

  // ---- init h: C-layout regs hc[n][j] (row b=4lg+j, col 32w+16n+lr) + LDS mirror ----
  float hc[2][4];
  #pragma unroll
  for(int n=0;n<2;++n){
    int col = 32*w + 16*n + lr;
    #pragma unroll
    for(int j=0;j<4;++j){
      int b = 4*lg + j;
      hc[n][j] = (b < 8) ? h0[b*STATEsz + h*Dsz + col] : 0.f;
      h_a[b][col] = f2bf(hc[n][j]);
    }
  }

  // ---- depth-2 gate prefetch buffers: buf[g*4+j] = dword (n=0 lo, n=1 hi) ----
  const unsigned short* pt0 = projT + ((size_t)h*Ssz)*3072;
  unsigned int bufA[12], bufB[12];
  #pragma unroll
  for(int i=0;i<12;++i){ bufA[i]=0u; bufB[i]=0u; }
  auto loadbuf = [&](int tt, unsigned int (&buf)[12]){
    if (lg < 2 && tt < Ssz){
      const unsigned short* p = pt0 + (size_t)tt*3072 + w*32 + lr*2;
      #pragma unroll
      for(int g=0; g<3; ++g)
        #pragma unroll
        for(int j=0;j<4;++j)
          buf[g*4+j] = *(const unsigned int*)(p + g*1024 + (4*lg+j)*128);
    }
  };
  loadbuf(0, bufA);
  loadbuf(1, bufB);
  __syncthreads();

  auto body = [&](int st, unsigned int (&buf)[12]){
    // ---- phase 1: read h A-frags, matvecs for r and f gates ----
    bf16x8 af[4];
    #pragma unroll
    for(int k=0;k<4;++k) af[k] = *(const bf16x8*)(&h_a[lr][32*k + 8*lg]);
    f32x4 aR[2], aF[2];
    #pragma unroll
    for(int n=0;n<2;++n){ aR[n]=f32x4{0.f,0.f,0.f,0.f}; aF[n]=f32x4{0.f,0.f,0.f,0.f}; }
    #pragma unroll
    for(int k=0;k<4;++k){
      #pragma unroll
      for(int n=0;n<2;++n){
        aR[n] = __builtin_amdgcn_mfma_f32_16x16x32_bf16(af[k], wbR[n][k], aR[n], 0,0,0);
        aF[n] = __builtin_amdgcn_mfma_f32_16x16x32_bf16(af[k], wbF[n][k], aF[n], 0,0,0);
      }
    }
    // extract gate inputs (vmcnt wait lands here, ~2 steps of slack), gates, rh
    float zz[2][4], ffv[2][4];
    #pragma unroll
    for(int n=0;n<2;++n){
      int col = 32*w + 16*n + lr;
      #pragma unroll
      for(int j=0;j<4;++j){
        float zt = n ? hiF(buf[0+j]) : loF(buf[0+j]);
        float ft = n ? hiF(buf[4+j]) : loF(buf[4+j]);
        float rt = n ? hiF(buf[8+j]) : loF(buf[8+j]);
        zz[n][j] = zt;
        float r  = sigmoid_(rt + aR[n][j]);
        ffv[n][j]= sigmoid_(ft + aF[n][j]);
        rh_a[4*lg+j][col] = f2bf(r * hc[n][j]);
      }
    }
    // reissue prefetch for st+2 (buffers fully consumed above)
    loadbuf(st+2, buf);
    asm volatile("s_waitcnt lgkmcnt(0)" ::: "memory");
    __builtin_amdgcn_s_barrier();
    asm volatile("" ::: "memory");
    // ---- phase 2: candidate matvec on r*h ----
    bf16x8 arf[4];
    #pragma unroll
    for(int k=0;k<4;++k) arf[k] = *(const bf16x8*)(&rh_a[lr][32*k + 8*lg]);
    f32x4 aC[2];
    #pragma unroll
    for(int n=0;n<2;++n) aC[n]=f32x4{0.f,0.f,0.f,0.f};
    #pragma unroll
    for(int k=0;k<4;++k){
      #pragma unroll
      for(int n=0;n<2;++n)
        aC[n] = __builtin_amdgcn_mfma_f32_16x16x32_bf16(arf[k], wbS[n][k], aC[n], 0,0,0);
    }
    // h update + publish
    #pragma unroll
    for(int n=0;n<2;++n){
      int col = 32*w + 16*n + lr;
      #pragma unroll
      for(int j=0;j<4;++j){
        float c = tanh_(zz[n][j] + aC[n][j]);
        float f = ffv[n][j];
        float hn = f*hc[n][j] + (1.f - f)*c;
        hc[n][j] = hn;
        int b = 4*lg + j;
        unsigned short hb = f2bf(hn);
        h_a[b][col] = hb;
        if (b < 8) hs[(((size_t)b*Ssz + st) << 10) + h*Dsz + col] = hb;
      }
    }
    asm volatile("s_waitcnt lgkmcnt(0)" ::: "memory");
    __builtin_amdgcn_s_barrier();
    asm volatile("" ::: "memory");
  };

  for(int st=0; st<Ssz; st+=2){
    body(st,   bufA);
    body(st+1, bufB);
  }
  #pragma unroll
  for(int n=0;n<2;++n){
    int col = 32*w + 16*n + lr;
    #pragma unroll
    for(int j=0;j<4;++j){
      int b = 4*lg + j;
      if (b < 8) hT[b*STATEsz + h*Dsz + col] = hc[n][j];
    }
  }
}

// ---------------- launch ----------------
// ws layout (bytes):                      size
//   xbf   @ 0          bf16[8192*1024]    16,777,216
//   WiT   @ 16777216   bf16[3072*1024]     6,291,456
//   WoT   @ 23068672   bf16[1024*1024]     2,097,152
//   projT @ 25165824   bf16[8*1024*3*8*128] 50,331,648
//   hs    @ 75497472   bf16[8192*1024]    16,777,216
// total 92,274,688 B
extern "C" void kernel_launch(void* const* d_in, const int* in_sizes, int n_in,
                              void* d_out, int out_size, void* d_ws, size_t ws_size,
                              hipStream_t stream){
  const float* x   = (const float*)d_in[0];
  const float* h0  = (const float*)d_in[1];
  const float* Wi  = (const float*)d_in[2];
  const float* bi  = (const float*)d_in[3];
  const float* Wst = (const float*)d_in[4];
  const float* Wfg = (const float*)d_in[5];
  const float* Wrs = (const float*)d_in[6];
  const float* Wo  = (const float*)d_in[7];
  float* out = (float*)d_out;
  float* hT  = out + (size_t)Bsz*Ssz*1024;

  char* ws = (char*)d_ws;
  unsigned short* xbf   = (unsigned short*)(ws);
  unsigned short* WiT   = (unsigned short*)(ws + 16777216);
  unsigned short* WoT   = (unsigned short*)(ws + 23068672);
  unsigned short* projT = (unsigned short*)(ws + 25165824);
  unsigned short* hsb   = (unsigned short*)(ws + 75497472);

  k_cast_bf16<<<dim3(8192), dim3(256), 0, stream>>>(x, xbf, 2097152);
  k_transpose_bf16<<<dim3(3072/32, 1024/32), dim3(32,8), 0, stream>>>(Wi, WiT, 1024, 3072);
  k_transpose_bf16<<<dim3(1024/32, 1024/32), dim3(32,8), 0, stream>>>(Wo, WoT, 1024, 1024);
  k_gemm<2,true><<<dim3(3072/128, 8192/128), dim3(256), 0, stream>>>(
      xbf, WiT, bi, projT, nullptr, 8192, 3072, 1024);
  k_rnn_mfma<<<dim3(8), dim3(256), 0, stream>>>(projT, h0, Wst, Wfg, Wrs, hsb, hT);
  k_gemm<0,false><<<dim3(1024/128, 8192/128), dim3(256), 0, stream>>>(
      hsb, WoT, nullptr, nullptr, out, 8192, 1024, 1024);
}

// Round 8
// 1809.497 us; speedup vs baseline: 1.5851x; 1.0515x over previous
//
#include <hip/hip_runtime.h>
#include <stdint.h>

// Problem constants (GRU_12764642803875)
#define Bsz 8
#define Ssz 1024
#define STATEsz 1024
#define Hsz 8
#define Dsz 128

typedef float  f32x4  __attribute__((ext_vector_type(4)));
typedef float  f32x2  __attribute__((ext_vector_type(2)));
typedef int    i32x4  __attribute__((ext_vector_type(4)));
typedef __bf16 bf16x8 __attribute__((ext_vector_type(8)));

__device__ __forceinline__ unsigned short f2bf(float f){
  unsigned int u = __float_as_uint(f);
  u = u + 0x7FFFu + ((u >> 16) & 1u);   // round-to-nearest-even
  return (unsigned short)(u >> 16);
}
__device__ __forceinline__ float bf2f(unsigned short s){
  return __uint_as_float(((unsigned int)s) << 16);
}
__device__ __forceinline__ float loF(unsigned int v){ return __uint_as_float(v << 16); }
__device__ __forceinline__ float hiF(unsigned int v){ return __uint_as_float(v & 0xffff0000u); }
__device__ __forceinline__ float sigmoid_(float x){ return 1.f/(1.f+__expf(-x)); }
__device__ __forceinline__ float tanh_(float x){ return 2.f/(1.f+__expf(-2.f*x)) - 1.f; }

#define MFMA16(a,b,c) __builtin_amdgcn_mfma_f32_16x16x32_bf16((a),(b),(c),0,0,0)

// ---------------- fp32 -> bf16 cast, 4-wide ----------------
__global__ void k_cast_bf16(const float* __restrict__ in, unsigned short* __restrict__ out, int n4){
  int i = blockIdx.x*blockDim.x + threadIdx.x;
  if (i >= n4) return;
  f32x4 v = ((const f32x4*)in)[i];
  ushort4 o;
  o.x = f2bf(v[0]); o.y = f2bf(v[1]); o.z = f2bf(v[2]); o.w = f2bf(v[3]);
  ((ushort4*)out)[i] = o;
}

// ---------------- fp32 [R][C] -> bf16 [C][R] transpose ----------------
__global__ void k_transpose_bf16(const float* __restrict__ in, unsigned short* __restrict__ out, int R, int C){
  __shared__ float tile[32][33];
  int c0 = blockIdx.x*32, r0 = blockIdx.y*32;
  int tx = threadIdx.x, ty = threadIdx.y;   // block (32,8)
  #pragma unroll
  for (int i=0;i<4;++i) tile[ty+8*i][tx] = in[(size_t)(r0+ty+8*i)*C + c0+tx];
  __syncthreads();
  #pragma unroll
  for (int i=0;i<4;++i) out[(size_t)(c0+ty+8*i)*R + r0+tx] = f2bf(tile[tx][ty+8*i]);
}

// ---------------- bf16 MFMA GEMM: C[M,N] = A[M,K] @ Bt[N,K]^T (+bias) ----------------
// MODE 0: f32 C row-major.  MODE 1: bf16 C row-major.
// MODE 2: bf16 scatter into projT[h][t][g][b][d] (N must be 3072, M = B*S).
template<int MODE, bool BIAS>
__global__ __launch_bounds__(256) void k_gemm(
    const unsigned short* __restrict__ A, const unsigned short* __restrict__ Bt,
    const float* __restrict__ bias, unsigned short* __restrict__ Cb, float* __restrict__ Cf,
    int M, int N, int K){
  __shared__ unsigned short As[128][40];
  __shared__ unsigned short Bs[128][40];
  int t = threadIdx.x;
  int l = t & 63, w = t >> 6, wm = w >> 1, wn = w & 1;
  int m0 = blockIdx.y*128, n0 = blockIdx.x*128;
  f32x4 acc[4][4];
  #pragma unroll
  for(int a=0;a<4;++a)
    #pragma unroll
    for(int b=0;b<4;++b){ acc[a][b][0]=0.f; acc[a][b][1]=0.f; acc[a][b][2]=0.f; acc[a][b][3]=0.f; }
  int lr = l & 15, lk = (l >> 4)*8;
  for(int k0=0;k0<K;k0+=32){
    #pragma unroll
    for(int it=0; it<2; ++it){              // stage 128x32 bf16 for A and Bt
      int idx = t + 256*it, r = idx>>2, q = idx&3;
      i32x4 av = *(const i32x4*)(A  + (size_t)(m0+r)*K + k0 + q*8);
      i32x4 bv = *(const i32x4*)(Bt + (size_t)(n0+r)*K + k0 + q*8);
      *(i32x4*)(&As[r][q*8]) = av;
      *(i32x4*)(&Bs[r][q*8]) = bv;
    }
    __syncthreads();
    bf16x8 af[4], bfv[4];
    #pragma unroll
    for(int mi=0;mi<4;++mi) af[mi]  = *(const bf16x8*)(&As[wm*64+mi*16+lr][lk]);
    #pragma unroll
    for(int ni=0;ni<4;++ni) bfv[ni] = *(const bf16x8*)(&Bs[wn*64+ni*16+lr][lk]);
    #pragma unroll
    for(int mi=0;mi<4;++mi)
      #pragma unroll
      for(int ni=0;ni<4;++ni)
        acc[mi][ni] = MFMA16(af[mi], bfv[ni], acc[mi][ni]);
    __syncthreads();
  }
  // C/D layout: col = lane&15, row = (lane>>4)*4 + j  [m89-verified]
  int cr0 = (l>>4)*4;
  #pragma unroll
  for(int mi=0;mi<4;++mi){
    #pragma unroll
    for(int ni=0;ni<4;++ni){
      int col = n0 + wn*64 + ni*16 + lr;
      float bv = BIAS ? bias[col] : 0.f;
      #pragma unroll
      for(int j=0;j<4;++j){
        int row = m0 + wm*64 + mi*16 + cr0 + j;
        float v = acc[mi][ni][j] + bv;
        if (MODE == 0) Cf[(size_t)row*N + col] = v;
        else if (MODE == 1) Cb[(size_t)row*N + col] = f2bf(v);
        else {
          int b = row >> 10, tt = row & 1023;
          int g = col >> 10, hh = (col >> 7) & 7, d = col & 127;
          size_t idx = ((((size_t)hh*1024 + tt)*3 + g) << 10) + b*128 + d;
          Cb[idx] = f2bf(v);
        }
      }
    }
  }
}

// ---------------- recurrence via MFMA: 8 blocks (one per head), 256 threads ----------------
// 4 waves; wave w owns col pairs col(n,lr) = 32w + 2*lr + n  (n=0,1). M=16 = 8 batch + 8 pad.
// Phase 1: aR (8 MFMA, 2+2 chains). Phase 2: aF (register-only inputs -> issues under
// arf ds_read latency) + aC. rh/h' published as conflict-free dword LDS writes
// (32 writing lanes -> 32 distinct banks). Depth-2 gate prefetch; raw barriers with
// lgkmcnt(0) only (global loads/stores stay in flight).
__global__ __launch_bounds__(256, 1) void k_rnn_mfma(
    const unsigned short* __restrict__ projT,  // [8][1024][3][8][128] bf16
    const float* __restrict__ h0,
    const float* __restrict__ Wst, const float* __restrict__ Wfg, const float* __restrict__ Wrs,
    unsigned short* __restrict__ hs, float* __restrict__ hT){
  const int h = blockIdx.x;            // head
  const int t0 = threadIdx.x;
  const int l = t0 & 63, w = t0 >> 6;  // lane, wave (0..3)
  const int lr = l & 15;               // A-row / C-col-index (within tile)
  const int lg = l >> 4;               // quarter-wave group
  const int c0 = 32*w + 2*lr;          // first of this lane's column pair

  __shared__ unsigned short h_a[16][136];
  __shared__ unsigned short rh_a[16][136];

  // ---- weight B-frags: wbX[n][k][j] = W[32k+8lg+j][c0+n] (n-pairs via f32x2 loads) ----
  bf16x8 wbR[2][4], wbF[2][4], wbS[2][4];
  {
    const float* pR = Wrs + h*16384 + c0;
    const float* pF = Wfg + h*16384 + c0;
    const float* pS = Wst + h*16384 + c0;
    #pragma unroll
    for(int k=0;k<4;++k){
      #pragma unroll
      for(int j=0;j<8;++j){
        int din = 32*k + 8*lg + j;
        f32x2 vR = *(const f32x2*)(pR + din*128);
        f32x2 vF = *(const f32x2*)(pF + din*128);
        f32x2 vS = *(const f32x2*)(pS + din*128);
        wbR[0][k][j] = (__bf16)vR[0]; wbR[1][k][j] = (__bf16)vR[1];
        wbF[0][k][j] = (__bf16)vF[0]; wbF[1][k][j] = (__bf16)vF[1];
        wbS[0][k][j] = (__bf16)vS[0]; wbS[1][k][j] = (__bf16)vS[1];
      }
    }
  }

  // ---- zero LDS (pad rows must stay 0), then init h ----
  for(int i=t0; i<16*136; i+=256){
    ((unsigned short*)h_a)[i] = 0;
    ((unsigned short*)rh_a)[i] = 0;
  }
  __syncthreads();
  float hc[2][4];
  #pragma unroll
  for(int n=0;n<2;++n)
    #pragma unroll
    for(int j=0;j<4;++j) hc[n][j] = 0.f;
  if (lg < 2){
    #pragma unroll
    for(int j=0;j<4;++j){
      int b = 4*lg + j;
      f32x2 v = *(const f32x2*)(h0 + b*STATEsz + h*Dsz + c0);
      hc[0][j] = v[0]; hc[1][j] = v[1];
      unsigned int pk = (unsigned int)f2bf(v[0]) | ((unsigned int)f2bf(v[1]) << 16);
      *(unsigned int*)(&h_a[b][c0]) = pk;
    }
  }

  // ---- depth-2 gate prefetch: buf[g*4+j] = dword (col pair) ----
  const unsigned short* pt0 = projT + ((size_t)h*Ssz)*3072;
  unsigned int bufA[12], bufB[12];
  #pragma unroll
  for(int i=0;i<12;++i){ bufA[i]=0u; bufB[i]=0u; }
  auto loadbuf = [&](int tt, unsigned int (&buf)[12]){
    if (lg < 2 && tt < Ssz){
      const unsigned short* p = pt0 + (size_t)tt*3072 + (4*lg)*128 + c0;
      #pragma unroll
      for(int g=0; g<3; ++g)
        #pragma unroll
        for(int j=0;j<4;++j)
          buf[g*4+j] = *(const unsigned int*)(p + g*1024 + j*128);
    }
  };
  loadbuf(0, bufA);
  loadbuf(1, bufB);
  __syncthreads();

  auto body = [&](int st, unsigned int (&buf)[12]){
    // ---- phase 1: h A-frags + aR matvec (2 chains of 2) ----
    bf16x8 af0 = *(const bf16x8*)(&h_a[lr][ 0 + 8*lg]);
    bf16x8 af1 = *(const bf16x8*)(&h_a[lr][32 + 8*lg]);
    bf16x8 af2 = *(const bf16x8*)(&h_a[lr][64 + 8*lg]);
    bf16x8 af3 = *(const bf16x8*)(&h_a[lr][96 + 8*lg]);
    const f32x4 z4 = {0.f,0.f,0.f,0.f};
    f32x4 aR0[2], aR1[2];
    #pragma unroll
    for(int n=0;n<2;++n){
      aR0[n] = MFMA16(af0, wbR[n][0], z4);
      aR1[n] = MFMA16(af2, wbR[n][2], z4);
      aR0[n] = MFMA16(af1, wbR[n][1], aR0[n]);
      aR1[n] = MFMA16(af3, wbR[n][3], aR1[n]);
    }
    // r gate + rh publish (conflict-free dword writes, real rows only)
    float rv[2][4];
    #pragma unroll
    for(int j=0;j<4;++j){
      unsigned int rt = buf[8+j];
      rv[0][j] = sigmoid_(loF(rt) + aR0[0][j] + aR1[0][j]);
      rv[1][j] = sigmoid_(hiF(rt) + aR0[1][j] + aR1[1][j]);
    }
    if (lg < 2){
      #pragma unroll
      for(int j=0;j<4;++j){
        unsigned int pk = (unsigned int)f2bf(rv[0][j]*hc[0][j])
                        | ((unsigned int)f2bf(rv[1][j]*hc[1][j]) << 16);
        *(unsigned int*)(&rh_a[4*lg+j][c0]) = pk;
      }
    }
    asm volatile("s_waitcnt lgkmcnt(0)" ::: "memory");
    __builtin_amdgcn_s_barrier();
    asm volatile("" ::: "memory");
    // ---- phase 2: arf reads; aF issues under their latency (register inputs only) ----
    bf16x8 ar0 = *(const bf16x8*)(&rh_a[lr][ 0 + 8*lg]);
    bf16x8 ar1 = *(const bf16x8*)(&rh_a[lr][32 + 8*lg]);
    bf16x8 ar2 = *(const bf16x8*)(&rh_a[lr][64 + 8*lg]);
    bf16x8 ar3 = *(const bf16x8*)(&rh_a[lr][96 + 8*lg]);
    f32x4 aF0[2], aF1[2], aC0[2], aC1[2];
    #pragma unroll
    for(int n=0;n<2;++n){
      aF0[n] = MFMA16(af0, wbF[n][0], z4);
      aF1[n] = MFMA16(af2, wbF[n][2], z4);
      aF0[n] = MFMA16(af1, wbF[n][1], aF0[n]);
      aF1[n] = MFMA16(af3, wbF[n][3], aF1[n]);
    }
    #pragma unroll
    for(int n=0;n<2;++n){
      aC0[n] = MFMA16(ar0, wbS[n][0], z4);
      aC1[n] = MFMA16(ar2, wbS[n][2], z4);
      aC0[n] = MFMA16(ar1, wbS[n][1], aC0[n]);
      aC1[n] = MFMA16(ar3, wbS[n][3], aC1[n]);
    }
    // f, c, h update
    #pragma unroll
    for(int j=0;j<4;++j){
      unsigned int zt = buf[0+j], ft = buf[4+j];
      float f0 = sigmoid_(loF(ft) + aF0[0][j] + aF1[0][j]);
      float f1 = sigmoid_(hiF(ft) + aF0[1][j] + aF1[1][j]);
      float c0v = tanh_(loF(zt) + aC0[0][j] + aC1[0][j]);
      float c1v = tanh_(hiF(zt) + aC0[1][j] + aC1[1][j]);
      hc[0][j] = f0*hc[0][j] + (1.f - f0)*c0v;
      hc[1][j] = f1*hc[1][j] + (1.f - f1)*c1v;
    }
    loadbuf(st+2, buf);   // reissue prefetch (buf fully consumed)
    if (lg < 2){
      #pragma unroll
      for(int j=0;j<4;++j){
        int b = 4*lg + j;
        unsigned int pk = (unsigned int)f2bf(hc[0][j])
                        | ((unsigned int)f2bf(hc[1][j]) << 16);
        *(unsigned int*)(&h_a[b][c0]) = pk;
        *(unsigned int*)(hs + (((size_t)b*Ssz + st) << 10) + h*Dsz + c0) = pk;
      }
    }
    asm volatile("s_waitcnt lgkmcnt(0)" ::: "memory");
    __builtin_amdgcn_s_barrier();
    asm volatile("" ::: "memory");
  };

  for(int st=0; st<Ssz; st+=2){
    body(st,   bufA);
    body(st+1, bufB);
  }
  if (lg < 2){
    #pragma unroll
    for(int j=0;j<4;++j){
      int b = 4*lg + j;
      f32x2 v = {hc[0][j], hc[1][j]};
      *(f32x2*)(&hT[b*STATEsz + h*Dsz + c0]) = v;
    }
  }
}

// ---------------- launch ----------------
// ws layout (bytes):                      size
//   xbf   @ 0          bf16[8192*1024]    16,777,216
//   WiT   @ 16777216   bf16[3072*1024]     6,291,456
//   WoT   @ 23068672   bf16[1024*1024]     2,097,152
//   projT @ 25165824   bf16[8*1024*3*8*128] 50,331,648
//   hs    @ 75497472   bf16[8192*1024]    16,777,216
// total 92,274,688 B
extern "C" void kernel_launch(void* const* d_in, const int* in_sizes, int n_in,
                              void* d_out, int out_size, void* d_ws, size_t ws_size,
                              hipStream_t stream){
  const float* x   = (const float*)d_in[0];
  const float* h0  = (const float*)d_in[1];
  const float* Wi  = (const float*)d_in[2];
  const float* bi  = (const float*)d_in[3];
  const float* Wst = (const float*)d_in[4];
  const float* Wfg = (const float*)d_in[5];
  const float* Wrs = (const float*)d_in[6];
  const float* Wo  = (const float*)d_in[7];
  float* out = (float*)d_out;
  float* hT  = out + (size_t)Bsz*Ssz*1024;

  char* ws = (char*)d_ws;
  unsigned short* xbf   = (unsigned short*)(ws);
  unsigned short* WiT   = (unsigned short*)(ws + 16777216);
  unsigned short* WoT   = (unsigned short*)(ws + 23068672);
  unsigned short* projT = (unsigned short*)(ws + 25165824);
  unsigned short* hsb   = (unsigned short*)(ws + 75497472);

  k_cast_bf16<<<dim3(8192), dim3(256), 0, stream>>>(x, xbf, 2097152);
  k_transpose_bf16<<<dim3(3072/32, 1024/32), dim3(32,8), 0, stream>>>(Wi, WiT, 1024, 3072);
  k_transpose_bf16<<<dim3(1024/32, 1024/32), dim3(32,8), 0, stream>>>(Wo, WoT, 1024, 1024);
  k_gemm<2,true><<<dim3(3072/128, 8192/128), dim3(256), 0, stream>>>(
      xbf, WiT, bi, projT, nullptr, 8192, 3072, 1024);
  k_rnn_mfma<<<dim3(8), dim3(256), 0, stream>>>(projT, h0, Wst, Wfg, Wrs, hsb, hT);
  k_gemm<0,false><<<dim3(1024/128, 8192/128), dim3(256), 0, stream>>>(
      hsb, WoT, nullptr, nullptr, out, 8192, 1024, 1024);
}